// Round 13
// baseline (628.479 us; speedup 1.0000x reference)
//
#include <hip/hip_runtime.h>

#define NS 131072
#define KC 8
typedef unsigned long long u64;

#define LD4(P) (*reinterpret_cast<const float4*>(&sm[(P)]))
#define ST4(P) (*reinterpret_cast<float4*>(&sm[(P)]))
#define GL4(P) (*reinterpret_cast<const float4*>(&(P)))
#define GL2(P) (*reinterpret_cast<const float2*>(&(P)))

#define FMA4(ACCR, AV, B) do { \
  ACCR[0]=fmaf((AV),(B).x,ACCR[0]); ACCR[1]=fmaf((AV),(B).y,ACCR[1]); \
  ACCR[2]=fmaf((AV),(B).z,ACCR[2]); ACCR[3]=fmaf((AV),(B).w,ACCR[3]); } while(0)

// 4-wide K step: A from per-wave LDS arena (rows st+4m, broadcast: 4 distinct
// addrs/instr), B from GLOBAL (L1/L2-cached weights; one instr fetches the
// full 64-col row spread over lanes). Each b float4 reused 8x in registers.
#define K4G(ACC, ABASE, ASTR, AK, BROWPTR, BSTR, JO) do { \
  const float4 b0 = GL4((BROWPTR)[0*(BSTR) + (JO)]); \
  const float4 b1 = GL4((BROWPTR)[1*(BSTR) + (JO)]); \
  const float4 b2 = GL4((BROWPTR)[2*(BSTR) + (JO)]); \
  const float4 b3 = GL4((BROWPTR)[3*(BSTR) + (JO)]); \
  _Pragma("unroll") \
  for (int m_ = 0; m_ < 8; ++m_) { \
    const float4 av = LD4((ABASE)+(st+4*m_)*(ASTR)+(AK)*4); \
    FMA4(ACC[m_], av.x, b0); FMA4(ACC[m_], av.y, b1); \
    FMA4(ACC[m_], av.z, b2); FMA4(ACC[m_], av.w, b3); } \
} while(0)

#define INIT84(ACC, BPTR, OFF) do { \
  const float4 u_ = *reinterpret_cast<const float4*>(&(BPTR)[(OFF)]); \
  _Pragma("unroll") for (int m_=0;m_<8;++m_){ \
    ACC[m_][0]=u_.x; ACC[m_][1]=u_.y; ACC[m_][2]=u_.z; ACC[m_][3]=u_.w; } } while(0)

#define RELU84(ACC) do { _Pragma("unroll") for (int m_=0;m_<8;++m_) \
  { _Pragma("unroll") for (int j_=0;j_<4;++j_) ACC[m_][j_]=fmaxf(ACC[m_][j_],0.f); } } while(0)

// write 8x4 reg tile into e-arena rows st+4m (stride 68), cols job..job+3
#define WRITE_E(ACC) do { _Pragma("unroll") for (int m_=0;m_<8;++m_){ \
  ST4(EA + (st+4*m_)*68 + job) = \
    make_float4(ACC[m_][0],ACC[m_][1],ACC[m_][2],ACC[m_][3]); } } while(0)

// ---------------------------------------------------------------------------
// Block = 1 wave (64 threads) = 32 samples. NO cross-wave LDS sharing ->
// no barriers; per-wave LDS ops are hardware-ordered. 11.3KB LDS ->
// 14 blocks/CU, every wave at an independent phase.
// lane l: ot = l&15 (4 cols job=ot*4), st = l>>4 (8 rows st+4m).
// Arena (words): XS [0,640) x-chunk/z/d [32][20]; EA [640,2816) e1/e2 [32][68].
// ---------------------------------------------------------------------------
#define XS  0
#define EA  640
#define SMW 2816

__global__ __launch_bounds__(64, 4) void k_enc(
    const float* __restrict__ x,
    const float* __restrict__ We1, const float* __restrict__ be1,
    const float* __restrict__ We2, const float* __restrict__ be2,
    const float* __restrict__ We3, const float* __restrict__ be3,
    const float* __restrict__ Wd1, const float* __restrict__ bd1,
    const float* __restrict__ Wd2, const float* __restrict__ bd2,
    const float* __restrict__ centers,
    float* __restrict__ out_z, float* __restrict__ out_q,
    float* __restrict__ xhat, float* __restrict__ rec, float* __restrict__ kld,
    int* __restrict__ cidx, int* __restrict__ counts)
{
    __shared__ float sm[SMW];
    const int l  = threadIdx.x;
    const int ot = l & 15, st = l >> 4;
    const int job = ot * 4;
    const int s0 = blockIdx.x * 32;
    const int xr = l >> 1, xcc = (l & 1) * 8;      // x-staging: row, col8

    // ================= L1: K=128, 8 chunks of 16 (x via LDS, W global) =====
    float acc1[8][4];
    INIT84(acc1, be1, job);
    {
        float4 rx0 = GL4(x[(size_t)(s0+xr)*128 + xcc]);
        float4 rx1 = GL4(x[(size_t)(s0+xr)*128 + xcc + 4]);
        #pragma unroll 1
        for (int c = 0; c < 8; ++c) {
            ST4(XS + xr*20 + xcc)     = rx0;
            ST4(XS + xr*20 + xcc + 4) = rx1;
            if (c < 7) {
                rx0 = GL4(x[(size_t)(s0+xr)*128 + (c+1)*16 + xcc]);
                rx1 = GL4(x[(size_t)(s0+xr)*128 + (c+1)*16 + xcc + 4]);
            }
            #pragma unroll
            for (int kc = 0; kc < 4; ++kc)
                K4G(acc1, XS, 20, kc, We1 + (size_t)(c*16 + kc*4)*64, 64, job);
        }
    }
    RELU84(acc1);
    WRITE_E(acc1);                 // e1 -> EA (in-order per-wave LDS)

    // ================= L2: K=64 straight (A=e1 LDS, B=We2 global) ==========
    {
        float acc2[8][4];
        INIT84(acc2, be2, job);
        #pragma unroll 2
        for (int kc = 0; kc < 16; ++kc)
            K4G(acc2, EA, 68, kc, We2 + (size_t)(kc*4)*64, 64, job);
        RELU84(acc2);
        WRITE_E(acc2);             // e2 overwrites e1 (reads precede writes)
    }

    // ================= L3: z, 1 col/lane (col = ot) ==========
    float zac[8];
    {   const float b3v = be3[ot];
        #pragma unroll
        for (int m = 0; m < 8; ++m) zac[m] = b3v; }
    #pragma unroll 2
    for (int kc = 0; kc < 16; ++kc) {
        const float w0 = We3[(kc*4+0)*16 + ot];
        const float w1 = We3[(kc*4+1)*16 + ot];
        const float w2 = We3[(kc*4+2)*16 + ot];
        const float w3 = We3[(kc*4+3)*16 + ot];
        #pragma unroll
        for (int m = 0; m < 8; ++m) {
            const float4 av = LD4(EA + (st + 4*m)*68 + kc*4);
            float s = zac[m];
            s = fmaf(av.x, w0, s); s = fmaf(av.y, w1, s);
            s = fmaf(av.z, w2, s); s = fmaf(av.w, w3, s);
            zac[m] = s;
        }
    }
    #pragma unroll
    for (int m = 0; m < 8; ++m)
        out_z[(size_t)(s0 + st + 4*m)*16 + ot] = zac[m];
    #pragma unroll
    for (int m = 0; m < 8; ++m) sm[XS + (st + 4*m)*20 + ot] = zac[m];

    // ========== lanes<32: student-t + softmax + argmax + counts (row l) =====
    if (l < 32) {
        const float4 z0 = LD4(XS + l*20 + 0), z1 = LD4(XS + l*20 + 4);
        const float4 z2 = LD4(XS + l*20 + 8), z3 = LD4(XS + l*20 + 12);
        const float zz[16] = {z0.x,z0.y,z0.z,z0.w, z1.x,z1.y,z1.z,z1.w,
                              z2.x,z2.y,z2.z,z2.w, z3.x,z3.y,z3.z,z3.w};
        float d2[KC];
        #pragma unroll
        for (int k = 0; k < KC; ++k) {
            float acc = 0.f;
            #pragma unroll
            for (int q = 0; q < 16; ++q) {
                const float dl = zz[q] - centers[k*16 + q];
                acc = fmaf(dl, dl, acc);
            }
            d2[k] = acc;
        }
        float lgt[KC], ex[KC];
        float mm = -1e30f;
        #pragma unroll
        for (int k = 0; k < KC; ++k) { lgt[k] = -log1pf(d2[k]); mm = fmaxf(mm, lgt[k]); }
        float ssum = 0.f;
        #pragma unroll
        for (int k = 0; k < KC; ++k) { ex[k] = expf(lgt[k] - mm); ssum += ex[k]; }
        const float inv = 1.f / ssum;
        float4* oq = reinterpret_cast<float4*>(&out_q[(size_t)(s0 + l)*8]);
        oq[0] = make_float4(ex[0]*inv, ex[1]*inv, ex[2]*inv, ex[3]*inv);
        oq[1] = make_float4(ex[4]*inv, ex[5]*inv, ex[6]*inv, ex[7]*inv);
        int ci = 0; float best = d2[0];
        #pragma unroll
        for (int k = 1; k < KC; ++k) if (d2[k] < best) { best = d2[k]; ci = k; }
        cidx[s0 + l] = ci;
        #pragma unroll
        for (int k = 0; k < KC; ++k) {
            const u64 mk = __ballot(ci == k);   // lanes>=32 inactive here
            if (l == 0 && mk) atomicAdd(&counts[k], (int)__popcll(mk));
        }
        kld[s0 + l] = 0.f;
    }

    // ================= decoder: d = relu(z Wd1 + bd1), col = ot =============
    {
        float w[16];
        #pragma unroll
        for (int k = 0; k < 16; ++k) w[k] = Wd1[k*16 + ot];
        const float bb = bd1[ot];
        float dac[8];
        #pragma unroll
        for (int m = 0; m < 8; ++m) {
            const int r = st + 4*m;
            float s = bb;
            #pragma unroll
            for (int kc = 0; kc < 4; ++kc) {
                const float4 av = LD4(XS + r*20 + kc*4);
                s = fmaf(av.x, w[kc*4+0], s); s = fmaf(av.y, w[kc*4+1], s);
                s = fmaf(av.z, w[kc*4+2], s); s = fmaf(av.w, w[kc*4+3], s);
            }
            dac[m] = fmaxf(s, 0.f);
        }
        #pragma unroll
        for (int m = 0; m < 8; ++m) sm[XS + (st + 4*m)*20 + ot] = dac[m];
    }

    // ================= xhat: K=16, N=128 (2 halves of 64) + rec =============
    float rp[8] = {0.f,0.f,0.f,0.f,0.f,0.f,0.f,0.f};
    #pragma unroll
    for (int h = 0; h < 2; ++h) {
        float accx[8][4];
        INIT84(accx, bd2, h*64 + job);
        #pragma unroll
        for (int kc = 0; kc < 4; ++kc)
            K4G(accx, XS, 20, kc, Wd2 + (size_t)(kc*4)*128 + h*64, 128, job);
        #pragma unroll
        for (int m = 0; m < 8; ++m) {
            const int r = st + 4*m;
            const float4 xa = GL4(x[(size_t)(s0+r)*128 + h*64 + job]);
            float df;
            df=accx[m][0]-xa.x; rp[m]=fmaf(df,df,rp[m]);
            df=accx[m][1]-xa.y; rp[m]=fmaf(df,df,rp[m]);
            df=accx[m][2]-xa.z; rp[m]=fmaf(df,df,rp[m]);
            df=accx[m][3]-xa.w; rp[m]=fmaf(df,df,rp[m]);
            *reinterpret_cast<float4*>(&xhat[(size_t)(s0+r)*128 + h*64 + job]) =
                make_float4(accx[m][0],accx[m][1],accx[m][2],accx[m][3]);
        }
    }
    #pragma unroll
    for (int m = 0; m < 8; ++m) {
        float v = rp[m];
        v += __shfl_xor(v, 1); v += __shfl_xor(v, 2);
        v += __shfl_xor(v, 4); v += __shfl_xor(v, 8);
        if (ot == 0) rec[s0 + st + 4*m] = v * (1.f/128.f);
    }
}

// ---------------------------------------------------------------------------
__global__ void k_scan(const int* __restrict__ counts,
                       int* __restrict__ bases, int* __restrict__ cursors)
{
    if (threadIdx.x == 0) {
        int acc = 0;
        for (int k = 0; k < KC; ++k) { bases[k] = acc; cursors[k] = acc; acc += counts[k]; }
    }
}

__global__ __launch_bounds__(256) void k_scatter(
    const int* __restrict__ cidx, int* __restrict__ cursors, int* __restrict__ seg)
{
    const int s = blockIdx.x * 256 + threadIdx.x;
    const int lane = threadIdx.x & 63;
    const int ci = cidx[s];
    #pragma unroll
    for (int k = 0; k < KC; ++k) {
        const u64 mk = __ballot(ci == k);
        if (ci == k) {
            const int leader = __ffsll(mk) - 1;
            int base = 0;
            if (lane == leader) base = atomicAdd(&cursors[k], (int)__popcll(mk));
            base = __shfl(base, leader, 64);
            seg[base + (int)__popcll(mk & (((u64)1 << lane) - 1))] = s;
        }
    }
}

// ---------------------------------------------------------------------------
// k_heads: 1-wave blocks, 32 gathered samples of block-uniform cluster kk.
// Wh1/Wh2 read from global (L1/L2); only gathered z/x staged in LDS.
// ---------------------------------------------------------------------------
__global__ __launch_bounds__(64, 4) void k_heads(
    const float* __restrict__ x, const float* __restrict__ zread,
    const float* __restrict__ Wh1, const float* __restrict__ bh1,
    const float* __restrict__ Wh2, const float* __restrict__ bh2,
    const int* __restrict__ counts, const int* __restrict__ bases,
    const int* __restrict__ seg,
    float* __restrict__ surv)
{
    __shared__ float sm[SMW];
    __shared__ int idxs[32];
    const int l  = threadIdx.x;
    const int ot = l & 15, st = l >> 4;
    const int job = ot * 4;
    const int xr = l >> 1, xcc = (l & 1) * 8;

    int kk = -1, chunk = 0, pref = 0;
    #pragma unroll
    for (int q = 0; q < KC; ++q) {
        const int ck = (counts[q] + 31) >> 5;
        if (kk < 0) {
            if ((int)blockIdx.x < pref + ck) { kk = q; chunk = (int)blockIdx.x - pref; }
            pref += ck;
        }
    }
    if (kk < 0) return;
    kk    = __builtin_amdgcn_readfirstlane(kk);
    chunk = __builtin_amdgcn_readfirstlane(chunk);
    const int cnt  = __builtin_amdgcn_readfirstlane(counts[kk]);
    const int base = __builtin_amdgcn_readfirstlane(bases[kk]);

    if (l < 32) {
        const int i = chunk*32 + l;
        idxs[l] = seg[base + ((i < cnt) ? i : (cnt - 1))];
    }
    const int irow = idxs[xr];     // per-wave in-order LDS: write -> read OK

    // ================= head L1: K=144 (z 16 + x 128), W global =============
    float acc1[8][4];
    INIT84(acc1, bh1, (size_t)kk*64 + job);
    {   // stage gathered z [32][16] -> XS
        ST4(XS + xr*20 + xcc)     = GL4(zread[(size_t)irow*16 + xcc]);
        ST4(XS + xr*20 + xcc + 4) = GL4(zread[(size_t)irow*16 + xcc + 4]);
        #pragma unroll
        for (int kc = 0; kc < 4; ++kc)
            K4G(acc1, XS, 20, kc, Wh1 + ((size_t)kk*144 + kc*4)*64, 64, job);
        float4 rx0 = GL4(x[(size_t)irow*128 + xcc]);
        float4 rx1 = GL4(x[(size_t)irow*128 + xcc + 4]);
        #pragma unroll 1
        for (int c = 0; c < 8; ++c) {
            ST4(XS + xr*20 + xcc)     = rx0;
            ST4(XS + xr*20 + xcc + 4) = rx1;
            if (c < 7) {
                rx0 = GL4(x[(size_t)irow*128 + (c+1)*16 + xcc]);
                rx1 = GL4(x[(size_t)irow*128 + (c+1)*16 + xcc + 4]);
            }
            #pragma unroll
            for (int kc = 0; kc < 4; ++kc)
                K4G(acc1, XS, 20, kc,
                    Wh1 + ((size_t)kk*144 + 16 + c*16 + kc*4)*64, 64, job);
        }
    }
    RELU84(acc1);
    WRITE_E(acc1);                 // h1 -> EA

    // ================= head L2: K=64, B = Wh2 global (guarded float2) ======
    float acc2[8][4];
    {
        #pragma unroll
        for (int m = 0; m < 8; ++m) {
            acc2[m][0] = (job+0 < 50) ? bh2[(size_t)kk*50 + job+0] : 0.f;
            acc2[m][1] = (job+1 < 50) ? bh2[(size_t)kk*50 + job+1] : 0.f;
            acc2[m][2] = (job+2 < 50) ? bh2[(size_t)kk*50 + job+2] : 0.f;
            acc2[m][3] = (job+3 < 50) ? bh2[(size_t)kk*50 + job+3] : 0.f;
        }
    }
    #define MKB(BV, KR) float4 BV; { \
        const float* wp_ = Wh2 + ((size_t)kk*64 + (KR))*50; \
        if (job < 50)     { const float2 p_ = GL2(wp_[job]);     BV.x = p_.x; BV.y = p_.y; } \
        else              { BV.x = 0.f; BV.y = 0.f; } \
        if (job + 2 < 50) { const float2 p_ = GL2(wp_[job + 2]); BV.z = p_.x; BV.w = p_.y; } \
        else              { BV.z = 0.f; BV.w = 0.f; } }
    #pragma unroll 2
    for (int kc = 0; kc < 16; ++kc) {
        MKB(b0, kc*4 + 0); MKB(b1, kc*4 + 1);
        MKB(b2, kc*4 + 2); MKB(b3, kc*4 + 3);
        #pragma unroll
        for (int m = 0; m < 8; ++m) {
            const float4 av = LD4(EA + (st + 4*m)*68 + kc*4);
            FMA4(acc2[m], av.x, b0); FMA4(acc2[m], av.y, b1);
            FMA4(acc2[m], av.z, b2); FMA4(acc2[m], av.w, b3);
        }
    }
    #undef MKB

    // ================= store surv (cols < 50, rows < cnt) ===================
    #pragma unroll
    for (int m = 0; m < 8; ++m) {
        const int r = st + 4*m;
        if (chunk*32 + r < cnt) {
            float* so = &surv[(size_t)idxs[r]*50 + job];   // 8B-aligned
            if (ot < 12) {
                *reinterpret_cast<float2*>(&so[0]) = make_float2(acc2[m][0], acc2[m][1]);
                *reinterpret_cast<float2*>(&so[2]) = make_float2(acc2[m][2], acc2[m][3]);
            } else if (ot == 12) {
                *reinterpret_cast<float2*>(&so[0]) = make_float2(acc2[m][0], acc2[m][1]);
            }
        }
    }
}

// ---------------------------------------------------------------------------
extern "C" void kernel_launch(void* const* d_in, const int* in_sizes, int n_in,
                              void* d_out, int out_size, void* d_ws, size_t ws_size,
                              hipStream_t stream)
{
    const float* x   = (const float*)d_in[0];
    const float* We1 = (const float*)d_in[1];
    const float* be1 = (const float*)d_in[2];
    const float* We2 = (const float*)d_in[3];
    const float* be2 = (const float*)d_in[4];
    const float* We3 = (const float*)d_in[5];
    const float* be3 = (const float*)d_in[6];
    const float* Wd1 = (const float*)d_in[7];
    const float* bd1 = (const float*)d_in[8];
    const float* Wd2 = (const float*)d_in[9];
    const float* bd2 = (const float*)d_in[10];
    const float* Wh1 = (const float*)d_in[11];
    const float* bh1 = (const float*)d_in[12];
    const float* Wh2 = (const float*)d_in[13];
    const float* bh2 = (const float*)d_in[14];
    const float* cen = (const float*)d_in[15];
    float* out = (float*)d_out;

    float* out_z  = out;
    float* out_q  = out + (size_t)NS * 16;
    float* out_sv = out + (size_t)NS * 24;
    float* out_xh = out + (size_t)NS * 74;
    float* out_rc = out + (size_t)NS * 202;
    float* out_kl = out + (size_t)NS * 203;

    int* cidx    = (int*)d_ws;       // [NS]
    int* counts  = cidx + NS;        // [8]
    int* bases   = counts + KC;      // [8]
    int* cursors = bases + KC;       // [8]
    int* seg     = cursors + KC;     // [NS]

    hipMemsetAsync(counts, 0, KC * sizeof(int), stream);

    k_enc<<<dim3(NS / 32), dim3(64), 0, stream>>>(
        x, We1, be1, We2, be2, We3, be3, Wd1, bd1, Wd2, bd2, cen,
        out_z, out_q, out_xh, out_rc, out_kl, cidx, counts);

    k_scan<<<dim3(1), dim3(64), 0, stream>>>(counts, bases, cursors);

    k_scatter<<<dim3(NS / 256), dim3(256), 0, stream>>>(cidx, cursors, seg);

    k_heads<<<dim3(NS / 32 + KC), dim3(64), 0, stream>>>(
        x, out_z, Wh1, bh1, Wh2, bh2, counts, bases, seg, out_sv);
}

// Round 14
// 585.804 us; speedup vs baseline: 1.0728x; 1.0728x over previous
//
#include <hip/hip_runtime.h>

#define NS 131072
#define KC 8
typedef unsigned long long u64;

#define LD4(P) (*reinterpret_cast<const float4*>(&sm[(P)]))
#define ST4(P) (*reinterpret_cast<float4*>(&sm[(P)]))
#define GL4(P) (*reinterpret_cast<const float4*>(&(P)))
#define GL2(P) (*reinterpret_cast<const float2*>(&(P)))

#define FMA4(ACCR, AV, B) do { \
  ACCR[0]=fmaf((AV),(B).x,ACCR[0]); ACCR[1]=fmaf((AV),(B).y,ACCR[1]); \
  ACCR[2]=fmaf((AV),(B).z,ACCR[2]); ACCR[3]=fmaf((AV),(B).w,ACCR[3]); } while(0)

// 4-wide K step: A from per-wave LDS arena (rows st+4m, broadcast: 4 distinct
// addrs/instr), B from GLOBAL (L1/L2-cached weights). Each b reused 8x.
#define K4G(ACC, ABASE, ASTR, AK, BROWPTR, BSTR, JO) do { \
  const float4 b0 = GL4((BROWPTR)[0*(BSTR) + (JO)]); \
  const float4 b1 = GL4((BROWPTR)[1*(BSTR) + (JO)]); \
  const float4 b2 = GL4((BROWPTR)[2*(BSTR) + (JO)]); \
  const float4 b3 = GL4((BROWPTR)[3*(BSTR) + (JO)]); \
  _Pragma("unroll") \
  for (int m_ = 0; m_ < 8; ++m_) { \
    const float4 av = LD4((ABASE)+(st+4*m_)*(ASTR)+(AK)*4); \
    FMA4(ACC[m_], av.x, b0); FMA4(ACC[m_], av.y, b1); \
    FMA4(ACC[m_], av.z, b2); FMA4(ACC[m_], av.w, b3); } \
} while(0)

#define INIT84(ACC, BPTR, OFF) do { \
  const float4 u_ = *reinterpret_cast<const float4*>(&(BPTR)[(OFF)]); \
  _Pragma("unroll") for (int m_=0;m_<8;++m_){ \
    ACC[m_][0]=u_.x; ACC[m_][1]=u_.y; ACC[m_][2]=u_.z; ACC[m_][3]=u_.w; } } while(0)

#define RELU84(ACC) do { _Pragma("unroll") for (int m_=0;m_<8;++m_) \
  { _Pragma("unroll") for (int j_=0;j_<4;++j_) ACC[m_][j_]=fmaxf(ACC[m_][j_],0.f); } } while(0)

// write 8x4 reg tile into e-arena rows st+4m (stride 68), cols job..job+3
#define WRITE_E(ACC) do { _Pragma("unroll") for (int m_=0;m_<8;++m_){ \
  ST4(EA + (st+4*m_)*68 + job) = \
    make_float4(ACC[m_][0],ACC[m_][1],ACC[m_][2],ACC[m_][3]); } } while(0)

// ---------------------------------------------------------------------------
// Block = 1 wave (64 threads) = 32 samples. No barriers (per-wave LDS is
// hardware-ordered). __launch_bounds__(64,2) -> VGPR cap 128 (r13 used (64,4)
// -> cap 64 -> spill storm; that was the regression, not the structure).
// lane l: ot = l&15 (4 cols job=ot*4), st = l>>4 (8 rows st+4m).
// Arena (words): XS [0,640) x-chunk/z/d [32][20]; EA [640,2816) e1/e2 [32][68].
// ---------------------------------------------------------------------------
#define XS  0
#define EA  640
#define SMW 2816

__global__ __launch_bounds__(64, 2) void k_enc(
    const float* __restrict__ x,
    const float* __restrict__ We1, const float* __restrict__ be1,
    const float* __restrict__ We2, const float* __restrict__ be2,
    const float* __restrict__ We3, const float* __restrict__ be3,
    const float* __restrict__ Wd1, const float* __restrict__ bd1,
    const float* __restrict__ Wd2, const float* __restrict__ bd2,
    const float* __restrict__ centers,
    float* __restrict__ out_z, float* __restrict__ out_q,
    float* __restrict__ xhat, float* __restrict__ rec, float* __restrict__ kld,
    int* __restrict__ cidx, int* __restrict__ counts)
{
    __shared__ float sm[SMW];
    const int l  = threadIdx.x;
    const int ot = l & 15, st = l >> 4;
    const int job = ot * 4;
    const int s0 = blockIdx.x * 32;
    const int xr = l >> 1, xcc = (l & 1) * 8;      // x-staging: row, col8

    // ================= L1: K=128, 8 chunks of 16 (x via LDS, W global) =====
    float acc1[8][4];
    INIT84(acc1, be1, job);
    {
        float4 rx0 = GL4(x[(size_t)(s0+xr)*128 + xcc]);
        float4 rx1 = GL4(x[(size_t)(s0+xr)*128 + xcc + 4]);
        #pragma unroll 1
        for (int c = 0; c < 8; ++c) {
            ST4(XS + xr*20 + xcc)     = rx0;
            ST4(XS + xr*20 + xcc + 4) = rx1;
            if (c < 7) {
                rx0 = GL4(x[(size_t)(s0+xr)*128 + (c+1)*16 + xcc]);
                rx1 = GL4(x[(size_t)(s0+xr)*128 + (c+1)*16 + xcc + 4]);
            }
            #pragma unroll
            for (int kc = 0; kc < 4; ++kc)
                K4G(acc1, XS, 20, kc, We1 + (size_t)(c*16 + kc*4)*64, 64, job);
        }
    }
    RELU84(acc1);
    WRITE_E(acc1);                 // e1 -> EA (in-order per-wave LDS)

    // ================= L2: K=64 straight (A=e1 LDS, B=We2 global) ==========
    {
        float acc2[8][4];
        INIT84(acc2, be2, job);
        #pragma unroll 2
        for (int kc = 0; kc < 16; ++kc)
            K4G(acc2, EA, 68, kc, We2 + (size_t)(kc*4)*64, 64, job);
        RELU84(acc2);
        WRITE_E(acc2);             // e2 overwrites e1 (reads precede writes)
    }

    // ================= L3: z, 1 col/lane (col = ot) ==========
    float zac[8];
    {   const float b3v = be3[ot];
        #pragma unroll
        for (int m = 0; m < 8; ++m) zac[m] = b3v; }
    #pragma unroll 2
    for (int kc = 0; kc < 16; ++kc) {
        const float w0 = We3[(kc*4+0)*16 + ot];
        const float w1 = We3[(kc*4+1)*16 + ot];
        const float w2 = We3[(kc*4+2)*16 + ot];
        const float w3 = We3[(kc*4+3)*16 + ot];
        #pragma unroll
        for (int m = 0; m < 8; ++m) {
            const float4 av = LD4(EA + (st + 4*m)*68 + kc*4);
            float s = zac[m];
            s = fmaf(av.x, w0, s); s = fmaf(av.y, w1, s);
            s = fmaf(av.z, w2, s); s = fmaf(av.w, w3, s);
            zac[m] = s;
        }
    }
    #pragma unroll
    for (int m = 0; m < 8; ++m)
        out_z[(size_t)(s0 + st + 4*m)*16 + ot] = zac[m];
    #pragma unroll
    for (int m = 0; m < 8; ++m) sm[XS + (st + 4*m)*20 + ot] = zac[m];

    // ========== lanes<32: student-t + softmax + argmax + counts (row l) =====
    if (l < 32) {
        const float4 z0 = LD4(XS + l*20 + 0), z1 = LD4(XS + l*20 + 4);
        const float4 z2 = LD4(XS + l*20 + 8), z3 = LD4(XS + l*20 + 12);
        const float zz[16] = {z0.x,z0.y,z0.z,z0.w, z1.x,z1.y,z1.z,z1.w,
                              z2.x,z2.y,z2.z,z2.w, z3.x,z3.y,z3.z,z3.w};
        float d2[KC];
        #pragma unroll
        for (int k = 0; k < KC; ++k) {
            float acc = 0.f;
            #pragma unroll
            for (int q = 0; q < 16; ++q) {
                const float dl = zz[q] - centers[k*16 + q];
                acc = fmaf(dl, dl, acc);
            }
            d2[k] = acc;
        }
        float lgt[KC], ex[KC];
        float mm = -1e30f;
        #pragma unroll
        for (int k = 0; k < KC; ++k) { lgt[k] = -log1pf(d2[k]); mm = fmaxf(mm, lgt[k]); }
        float ssum = 0.f;
        #pragma unroll
        for (int k = 0; k < KC; ++k) { ex[k] = expf(lgt[k] - mm); ssum += ex[k]; }
        const float inv = 1.f / ssum;
        float4* oq = reinterpret_cast<float4*>(&out_q[(size_t)(s0 + l)*8]);
        oq[0] = make_float4(ex[0]*inv, ex[1]*inv, ex[2]*inv, ex[3]*inv);
        oq[1] = make_float4(ex[4]*inv, ex[5]*inv, ex[6]*inv, ex[7]*inv);
        int ci = 0; float best = d2[0];
        #pragma unroll
        for (int k = 1; k < KC; ++k) if (d2[k] < best) { best = d2[k]; ci = k; }
        cidx[s0 + l] = ci;
        #pragma unroll
        for (int k = 0; k < KC; ++k) {
            const u64 mk = __ballot(ci == k);   // lanes>=32 inactive here
            if (l == 0 && mk) atomicAdd(&counts[k], (int)__popcll(mk));
        }
        kld[s0 + l] = 0.f;
    }

    // ================= decoder: d = relu(z Wd1 + bd1), col = ot =============
    {
        float w[16];
        #pragma unroll
        for (int k = 0; k < 16; ++k) w[k] = Wd1[k*16 + ot];
        const float bb = bd1[ot];
        float dac[8];
        #pragma unroll
        for (int m = 0; m < 8; ++m) {
            const int r = st + 4*m;
            float s = bb;
            #pragma unroll
            for (int kc = 0; kc < 4; ++kc) {
                const float4 av = LD4(XS + r*20 + kc*4);
                s = fmaf(av.x, w[kc*4+0], s); s = fmaf(av.y, w[kc*4+1], s);
                s = fmaf(av.z, w[kc*4+2], s); s = fmaf(av.w, w[kc*4+3], s);
            }
            dac[m] = fmaxf(s, 0.f);
        }
        #pragma unroll
        for (int m = 0; m < 8; ++m) sm[XS + (st + 4*m)*20 + ot] = dac[m];
    }

    // ================= xhat: K=16, N=128 (2 halves of 64) + rec =============
    float rp[8] = {0.f,0.f,0.f,0.f,0.f,0.f,0.f,0.f};
    #pragma unroll
    for (int h = 0; h < 2; ++h) {
        float accx[8][4];
        INIT84(accx, bd2, h*64 + job);
        #pragma unroll
        for (int kc = 0; kc < 4; ++kc)
            K4G(accx, XS, 20, kc, Wd2 + (size_t)(kc*4)*128 + h*64, 128, job);
        #pragma unroll
        for (int m = 0; m < 8; ++m) {
            const int r = st + 4*m;
            const float4 xa = GL4(x[(size_t)(s0+r)*128 + h*64 + job]);
            float df;
            df=accx[m][0]-xa.x; rp[m]=fmaf(df,df,rp[m]);
            df=accx[m][1]-xa.y; rp[m]=fmaf(df,df,rp[m]);
            df=accx[m][2]-xa.z; rp[m]=fmaf(df,df,rp[m]);
            df=accx[m][3]-xa.w; rp[m]=fmaf(df,df,rp[m]);
            *reinterpret_cast<float4*>(&xhat[(size_t)(s0+r)*128 + h*64 + job]) =
                make_float4(accx[m][0],accx[m][1],accx[m][2],accx[m][3]);
        }
    }
    #pragma unroll
    for (int m = 0; m < 8; ++m) {
        float v = rp[m];
        v += __shfl_xor(v, 1); v += __shfl_xor(v, 2);
        v += __shfl_xor(v, 4); v += __shfl_xor(v, 8);
        if (ot == 0) rec[s0 + st + 4*m] = v * (1.f/128.f);
    }
}

// ---------------------------------------------------------------------------
__global__ void k_scan(const int* __restrict__ counts,
                       int* __restrict__ bases, int* __restrict__ cursors)
{
    if (threadIdx.x == 0) {
        int acc = 0;
        for (int k = 0; k < KC; ++k) { bases[k] = acc; cursors[k] = acc; acc += counts[k]; }
    }
}

__global__ __launch_bounds__(256) void k_scatter(
    const int* __restrict__ cidx, int* __restrict__ cursors, int* __restrict__ seg)
{
    const int s = blockIdx.x * 256 + threadIdx.x;
    const int lane = threadIdx.x & 63;
    const int ci = cidx[s];
    #pragma unroll
    for (int k = 0; k < KC; ++k) {
        const u64 mk = __ballot(ci == k);
        if (ci == k) {
            const int leader = __ffsll(mk) - 1;
            int base = 0;
            if (lane == leader) base = atomicAdd(&cursors[k], (int)__popcll(mk));
            base = __shfl(base, leader, 64);
            seg[base + (int)__popcll(mk & (((u64)1 << lane) - 1))] = s;
        }
    }
}

// ---------------------------------------------------------------------------
// k_heads: 1-wave blocks, 32 gathered samples of block-uniform cluster kk.
// Wh1/Wh2 read from global (L1/L2); only gathered z/x staged in LDS.
// ---------------------------------------------------------------------------
__global__ __launch_bounds__(64, 2) void k_heads(
    const float* __restrict__ x, const float* __restrict__ zread,
    const float* __restrict__ Wh1, const float* __restrict__ bh1,
    const float* __restrict__ Wh2, const float* __restrict__ bh2,
    const int* __restrict__ counts, const int* __restrict__ bases,
    const int* __restrict__ seg,
    float* __restrict__ surv)
{
    __shared__ float sm[SMW];
    __shared__ int idxs[32];
    const int l  = threadIdx.x;
    const int ot = l & 15, st = l >> 4;
    const int job = ot * 4;
    const int xr = l >> 1, xcc = (l & 1) * 8;

    int kk = -1, chunk = 0, pref = 0;
    #pragma unroll
    for (int q = 0; q < KC; ++q) {
        const int ck = (counts[q] + 31) >> 5;
        if (kk < 0) {
            if ((int)blockIdx.x < pref + ck) { kk = q; chunk = (int)blockIdx.x - pref; }
            pref += ck;
        }
    }
    if (kk < 0) return;
    kk    = __builtin_amdgcn_readfirstlane(kk);
    chunk = __builtin_amdgcn_readfirstlane(chunk);
    const int cnt  = __builtin_amdgcn_readfirstlane(counts[kk]);
    const int base = __builtin_amdgcn_readfirstlane(bases[kk]);

    if (l < 32) {
        const int i = chunk*32 + l;
        idxs[l] = seg[base + ((i < cnt) ? i : (cnt - 1))];
    }
    const int irow = idxs[xr];     // per-wave in-order LDS: write -> read OK

    // ================= head L1: K=144 (z 16 + x 128), W global =============
    float acc1[8][4];
    INIT84(acc1, bh1, (size_t)kk*64 + job);
    {   // stage gathered z [32][16] -> XS
        ST4(XS + xr*20 + xcc)     = GL4(zread[(size_t)irow*16 + xcc]);
        ST4(XS + xr*20 + xcc + 4) = GL4(zread[(size_t)irow*16 + xcc + 4]);
        #pragma unroll
        for (int kc = 0; kc < 4; ++kc)
            K4G(acc1, XS, 20, kc, Wh1 + ((size_t)kk*144 + kc*4)*64, 64, job);
        float4 rx0 = GL4(x[(size_t)irow*128 + xcc]);
        float4 rx1 = GL4(x[(size_t)irow*128 + xcc + 4]);
        #pragma unroll 1
        for (int c = 0; c < 8; ++c) {
            ST4(XS + xr*20 + xcc)     = rx0;
            ST4(XS + xr*20 + xcc + 4) = rx1;
            if (c < 7) {
                rx0 = GL4(x[(size_t)irow*128 + (c+1)*16 + xcc]);
                rx1 = GL4(x[(size_t)irow*128 + (c+1)*16 + xcc + 4]);
            }
            #pragma unroll
            for (int kc = 0; kc < 4; ++kc)
                K4G(acc1, XS, 20, kc,
                    Wh1 + ((size_t)kk*144 + 16 + c*16 + kc*4)*64, 64, job);
        }
    }
    RELU84(acc1);
    WRITE_E(acc1);                 // h1 -> EA

    // ================= head L2: K=64, B = Wh2 global (guarded float2) ======
    float acc2[8][4];
    {
        #pragma unroll
        for (int m = 0; m < 8; ++m) {
            acc2[m][0] = (job+0 < 50) ? bh2[(size_t)kk*50 + job+0] : 0.f;
            acc2[m][1] = (job+1 < 50) ? bh2[(size_t)kk*50 + job+1] : 0.f;
            acc2[m][2] = (job+2 < 50) ? bh2[(size_t)kk*50 + job+2] : 0.f;
            acc2[m][3] = (job+3 < 50) ? bh2[(size_t)kk*50 + job+3] : 0.f;
        }
    }
    #define MKB(BV, KR) float4 BV; { \
        const float* wp_ = Wh2 + ((size_t)kk*64 + (KR))*50; \
        if (job < 50)     { const float2 p_ = GL2(wp_[job]);     BV.x = p_.x; BV.y = p_.y; } \
        else              { BV.x = 0.f; BV.y = 0.f; } \
        if (job + 2 < 50) { const float2 p_ = GL2(wp_[job + 2]); BV.z = p_.x; BV.w = p_.y; } \
        else              { BV.z = 0.f; BV.w = 0.f; } }
    #pragma unroll 2
    for (int kc = 0; kc < 16; ++kc) {
        MKB(b0, kc*4 + 0); MKB(b1, kc*4 + 1);
        MKB(b2, kc*4 + 2); MKB(b3, kc*4 + 3);
        #pragma unroll
        for (int m = 0; m < 8; ++m) {
            const float4 av = LD4(EA + (st + 4*m)*68 + kc*4);
            FMA4(acc2[m], av.x, b0); FMA4(acc2[m], av.y, b1);
            FMA4(acc2[m], av.z, b2); FMA4(acc2[m], av.w, b3);
        }
    }
    #undef MKB

    // ================= store surv (cols < 50, rows < cnt) ===================
    #pragma unroll
    for (int m = 0; m < 8; ++m) {
        const int r = st + 4*m;
        if (chunk*32 + r < cnt) {
            float* so = &surv[(size_t)idxs[r]*50 + job];   // 8B-aligned
            if (ot < 12) {
                *reinterpret_cast<float2*>(&so[0]) = make_float2(acc2[m][0], acc2[m][1]);
                *reinterpret_cast<float2*>(&so[2]) = make_float2(acc2[m][2], acc2[m][3]);
            } else if (ot == 12) {
                *reinterpret_cast<float2*>(&so[0]) = make_float2(acc2[m][0], acc2[m][1]);
            }
        }
    }
}

// ---------------------------------------------------------------------------
extern "C" void kernel_launch(void* const* d_in, const int* in_sizes, int n_in,
                              void* d_out, int out_size, void* d_ws, size_t ws_size,
                              hipStream_t stream)
{
    const float* x   = (const float*)d_in[0];
    const float* We1 = (const float*)d_in[1];
    const float* be1 = (const float*)d_in[2];
    const float* We2 = (const float*)d_in[3];
    const float* be2 = (const float*)d_in[4];
    const float* We3 = (const float*)d_in[5];
    const float* be3 = (const float*)d_in[6];
    const float* Wd1 = (const float*)d_in[7];
    const float* bd1 = (const float*)d_in[8];
    const float* Wd2 = (const float*)d_in[9];
    const float* bd2 = (const float*)d_in[10];
    const float* Wh1 = (const float*)d_in[11];
    const float* bh1 = (const float*)d_in[12];
    const float* Wh2 = (const float*)d_in[13];
    const float* bh2 = (const float*)d_in[14];
    const float* cen = (const float*)d_in[15];
    float* out = (float*)d_out;

    float* out_z  = out;
    float* out_q  = out + (size_t)NS * 16;
    float* out_sv = out + (size_t)NS * 24;
    float* out_xh = out + (size_t)NS * 74;
    float* out_rc = out + (size_t)NS * 202;
    float* out_kl = out + (size_t)NS * 203;

    int* cidx    = (int*)d_ws;       // [NS]
    int* counts  = cidx + NS;        // [8]
    int* bases   = counts + KC;      // [8]
    int* cursors = bases + KC;       // [8]
    int* seg     = cursors + KC;     // [NS]

    hipMemsetAsync(counts, 0, KC * sizeof(int), stream);

    k_enc<<<dim3(NS / 32), dim3(64), 0, stream>>>(
        x, We1, be1, We2, be2, We3, be3, Wd1, bd1, Wd2, bd2, cen,
        out_z, out_q, out_xh, out_rc, out_kl, cidx, counts);

    k_scan<<<dim3(1), dim3(64), 0, stream>>>(counts, bases, cursors);

    k_scatter<<<dim3(NS / 256), dim3(256), 0, stream>>>(cidx, cursors, seg);

    k_heads<<<dim3(NS / 32 + KC), dim3(64), 0, stream>>>(
        x, out_z, Wh1, bh1, Wh2, bh2, counts, bases, seg, out_sv);
}

// Round 15
// 458.614 us; speedup vs baseline: 1.3704x; 1.2773x over previous
//
#include <hip/hip_runtime.h>

#define NS 131072
#define KC 8
typedef unsigned long long u64;

#define LD4(P) (*reinterpret_cast<const float4*>(&sm[(P)]))
#define ST4(P) (*reinterpret_cast<float4*>(&sm[(P)]))
#define GL4(P) (*reinterpret_cast<const float4*>(&(P)))

#define FMA4(ACCR, AV, B) do { \
  ACCR[0]=fmaf((AV),(B).x,ACCR[0]); ACCR[1]=fmaf((AV),(B).y,ACCR[1]); \
  ACCR[2]=fmaf((AV),(B).z,ACCR[2]); ACCR[3]=fmaf((AV),(B).w,ACCR[3]); } while(0)

// 4-wide K step, 8 samples (rows st+8m) x 4 outputs (cols job..job+3).
#define K4(ACC, ABASE, ASTR, AK, BBASE, BSTR, JOFF, BK) do { \
  const float4 b0=LD4((BBASE)+((BK)*4+0)*(BSTR)+(JOFF)); \
  const float4 b1=LD4((BBASE)+((BK)*4+1)*(BSTR)+(JOFF)); \
  const float4 b2=LD4((BBASE)+((BK)*4+2)*(BSTR)+(JOFF)); \
  const float4 b3=LD4((BBASE)+((BK)*4+3)*(BSTR)+(JOFF)); \
  _Pragma("unroll") \
  for (int m_ = 0; m_ < 8; ++m_) { \
    const float4 av = LD4((ABASE)+(st+8*m_)*(ASTR)+(AK)*4); \
    FMA4(ACC[m_], av.x, b0); FMA4(ACC[m_], av.y, b1); \
    FMA4(ACC[m_], av.z, b2); FMA4(ACC[m_], av.w, b3); } \
} while(0)

#define INIT84(ACC, BPTR, OFF) do { \
  const float4 u_ = *reinterpret_cast<const float4*>(&(BPTR)[(OFF)]); \
  _Pragma("unroll") for (int m_=0;m_<8;++m_){ \
    ACC[m_][0]=u_.x; ACC[m_][1]=u_.y; ACC[m_][2]=u_.z; ACC[m_][3]=u_.w; } } while(0)

#define RELU84(ACC) do { _Pragma("unroll") for (int m_=0;m_<8;++m_) \
  { _Pragma("unroll") for (int j_=0;j_<4;++j_) ACC[m_][j_]=fmaxf(ACC[m_][j_],0.f); } } while(0)

#define WRITE_E(ACC) do { _Pragma("unroll") for (int m_=0;m_<8;++m_){ \
  ST4(EA + (st+8*m_)*68 + job) = \
    make_float4(ACC[m_][0],ACC[m_][1],ACC[m_][2],ACC[m_][3]); } } while(0)

// stage held registers into a given x-buffer / w-buffer
#define STAGE_XB(B) do { \
  ST4((B) + xr0*20 + xcc)     = rx0; \
  ST4((B) + xr0*20 + xcc + 4) = rx1; } while(0)
#define STAGE_WB(B) do { \
  ST4((B) + wr*68 + wcc)     = rw0; \
  ST4((B) + wr*68 + wcc + 4) = rw1; } while(0)

// ---------------------------------------------------------------------------
// Block = 64 samples x 128 threads. Double-buffered staging: per chunk, write
// chunk c+1 into the idle buffer + issue chunk c+2 global loads BEFORE
// computing chunk c -> staging and load latency hide under K4 compute; ONE
// barrier per chunk. lane: ot=t&15 (job=ot*4), st=t>>4 (rows st+8m).
// Arena (words): XA[0,1280) XB[1280,2560) x-chunks [64][20];
// WA[2560,3648) WB_[3648,4736) weight chunks [16][68];
// EA[4736,9088) e1/e2/h1 [64][68]; ZD=EA base reused as z/d [64][20].
// 9088 w = 35.5 KB -> 4 blocks/CU.
// ---------------------------------------------------------------------------
#define XA   0
#define XB   1280
#define WA   2560
#define WB_  3648
#define EA   4736
#define ZD   4736
#define SMW  9088

__global__ __launch_bounds__(128, 2) void k_enc(
    const float* __restrict__ x,
    const float* __restrict__ We1, const float* __restrict__ be1,
    const float* __restrict__ We2, const float* __restrict__ be2,
    const float* __restrict__ We3, const float* __restrict__ be3,
    const float* __restrict__ Wd1, const float* __restrict__ bd1,
    const float* __restrict__ Wd2, const float* __restrict__ bd2,
    const float* __restrict__ centers,
    float* __restrict__ out_z, float* __restrict__ out_q,
    float* __restrict__ xhat, float* __restrict__ rec, float* __restrict__ kld,
    int* __restrict__ cidx, int* __restrict__ counts)
{
    __shared__ float sm[SMW];
    const int t  = threadIdx.x;
    const int ot = t & 15, st = t >> 4;
    const int job = ot * 4;
    const int s0 = blockIdx.x * 64;
    const int xr0 = t >> 1, xcc = (t & 1) * 8;     // x-staging: row, col8
    const int wr  = t >> 3, wcc = (t & 7) * 8;     // W-staging: row, col8

    // ================= L1: K=128, 8 chunks, dbuf 1-barrier =================
    {
        float acc1[8][4];
        INIT84(acc1, be1, job);
        float4 rx0 = GL4(x[(size_t)(s0+xr0)*128 + xcc]);
        float4 rx1 = GL4(x[(size_t)(s0+xr0)*128 + xcc + 4]);
        float4 rw0 = GL4(We1[(size_t)wr*64 + wcc]);
        float4 rw1 = GL4(We1[(size_t)wr*64 + wcc + 4]);
        STAGE_XB(XA); STAGE_WB(WA);                 // chunk0
        rx0 = GL4(x[(size_t)(s0+xr0)*128 + 16 + xcc]);
        rx1 = GL4(x[(size_t)(s0+xr0)*128 + 16 + xcc + 4]);
        rw0 = GL4(We1[(size_t)(16 + wr)*64 + wcc]);
        rw1 = GL4(We1[(size_t)(16 + wr)*64 + wcc + 4]);
        __syncthreads();
        #pragma unroll 1
        for (int c = 0; c < 8; ++c) {
            const int XC = (c & 1) ? XB : XA, WC = (c & 1) ? WB_ : WA;
            const int XN = (c & 1) ? XA : XB, WN = (c & 1) ? WA : WB_;
            if (c < 7) { STAGE_XB(XN); STAGE_WB(WN); }   // chunk c+1 -> idle buf
            if (c < 6) {                                  // issue chunk c+2
                rx0 = GL4(x[(size_t)(s0+xr0)*128 + (c+2)*16 + xcc]);
                rx1 = GL4(x[(size_t)(s0+xr0)*128 + (c+2)*16 + xcc + 4]);
                rw0 = GL4(We1[(size_t)((c+2)*16 + wr)*64 + wcc]);
                rw1 = GL4(We1[(size_t)((c+2)*16 + wr)*64 + wcc + 4]);
            }
            #pragma unroll
            for (int kc = 0; kc < 4; ++kc) K4(acc1, XC, 20, kc, WC, 68, job, kc);
            __syncthreads();
        }
        RELU84(acc1);
        WRITE_E(acc1);             // e1 -> EA (intra-wave rows)
    }

    // ================= L2: K=64, 4 We2 chunks, dbuf 1-barrier ==============
    {
        float acc2[8][4];
        INIT84(acc2, be2, job);
        float4 rw0 = GL4(We2[(size_t)wr*64 + wcc]);
        float4 rw1 = GL4(We2[(size_t)wr*64 + wcc + 4]);
        STAGE_WB(WA);                               // chunk0
        rw0 = GL4(We2[(size_t)(16 + wr)*64 + wcc]);
        rw1 = GL4(We2[(size_t)(16 + wr)*64 + wcc + 4]);
        __syncthreads();                            // chunk0 + e1 visible
        #pragma unroll 1
        for (int c = 0; c < 4; ++c) {
            const int WC = (c & 1) ? WB_ : WA;
            const int WN = (c & 1) ? WA : WB_;
            if (c < 3) STAGE_WB(WN);
            if (c < 2) {
                rw0 = GL4(We2[(size_t)((c+2)*16 + wr)*64 + wcc]);
                rw1 = GL4(We2[(size_t)((c+2)*16 + wr)*64 + wcc + 4]);
            }
            #pragma unroll
            for (int kc = 0; kc < 4; ++kc) K4(acc2, EA, 68, c*4 + kc, WC, 68, job, kc);
            __syncthreads();
        }
        RELU84(acc2);
        WRITE_E(acc2);             // e2 overwrites e1 (intra-wave rows)
    }

    // ==== stage W3 -> XA, Wd1 -> XB, Wd2 halves -> WA/WB_ (all idle now) ====
    {   const int r3 = t >> 2, c3 = (t & 3) * 4;
        ST4(XA + r3*16 + c3)      = GL4(We3[(size_t)r3*16 + c3]);
        ST4(XA + (r3+32)*16 + c3) = GL4(We3[(size_t)(r3+32)*16 + c3]); }
    if (t < 64) ST4(XB + (t >> 2)*16 + (t & 3)*4) =
        GL4(Wd1[(t >> 2)*16 + (t & 3)*4]);
    ST4(WA  + wr*68 + wcc)     = GL4(Wd2[(size_t)wr*128 + wcc]);
    ST4(WA  + wr*68 + wcc + 4) = GL4(Wd2[(size_t)wr*128 + wcc + 4]);
    ST4(WB_ + wr*68 + wcc)     = GL4(Wd2[(size_t)wr*128 + 64 + wcc]);
    ST4(WB_ + wr*68 + wcc + 4) = GL4(Wd2[(size_t)wr*128 + 64 + wcc + 4]);
    __syncthreads();

    // ================= L3: z, K=64, 1 col/thread (col = ot) =================
    float zac[8];
    {   const float b3v = be3[ot];
        #pragma unroll
        for (int m = 0; m < 8; ++m) zac[m] = b3v; }
    #pragma unroll 2
    for (int kc = 0; kc < 16; ++kc) {
        const float w0 = sm[XA + (kc*4+0)*16 + ot];
        const float w1 = sm[XA + (kc*4+1)*16 + ot];
        const float w2 = sm[XA + (kc*4+2)*16 + ot];
        const float w3 = sm[XA + (kc*4+3)*16 + ot];
        #pragma unroll
        for (int m = 0; m < 8; ++m) {
            const float4 av = LD4(EA + (st + 8*m)*68 + kc*4);
            float s = zac[m];
            s = fmaf(av.x, w0, s); s = fmaf(av.y, w1, s);
            s = fmaf(av.z, w2, s); s = fmaf(av.w, w3, s);
            zac[m] = s;
        }
    }
    #pragma unroll
    for (int m = 0; m < 8; ++m)
        out_z[(size_t)(s0 + st + 8*m)*16 + ot] = zac[m];
    __syncthreads();               // all L3 reads of EA done -> z may overwrite
    #pragma unroll
    for (int m = 0; m < 8; ++m) sm[ZD + (st + 8*m)*20 + ot] = zac[m];
    __syncthreads();               // z visible cross-wave (d2 phase)

    // ======== wave 0 (t<64): student-t + softmax + argmax + counts ==========
    if (t < 64) {
        const float4 z0 = LD4(ZD + t*20 + 0), z1 = LD4(ZD + t*20 + 4);
        const float4 z2 = LD4(ZD + t*20 + 8), z3 = LD4(ZD + t*20 + 12);
        const float zz[16] = {z0.x,z0.y,z0.z,z0.w, z1.x,z1.y,z1.z,z1.w,
                              z2.x,z2.y,z2.z,z2.w, z3.x,z3.y,z3.z,z3.w};
        float d2[KC];
        #pragma unroll
        for (int k = 0; k < KC; ++k) {
            float acc = 0.f;
            #pragma unroll
            for (int l = 0; l < 16; ++l) {
                const float dl = zz[l] - centers[k*16 + l];
                acc = fmaf(dl, dl, acc);
            }
            d2[k] = acc;
        }
        float lgt[KC], ex[KC];
        float mm = -1e30f;
        #pragma unroll
        for (int k = 0; k < KC; ++k) { lgt[k] = -log1pf(d2[k]); mm = fmaxf(mm, lgt[k]); }
        float ssum = 0.f;
        #pragma unroll
        for (int k = 0; k < KC; ++k) { ex[k] = expf(lgt[k] - mm); ssum += ex[k]; }
        const float inv = 1.f / ssum;
        float4* oq = reinterpret_cast<float4*>(&out_q[(size_t)(s0 + t)*8]);
        oq[0] = make_float4(ex[0]*inv, ex[1]*inv, ex[2]*inv, ex[3]*inv);
        oq[1] = make_float4(ex[4]*inv, ex[5]*inv, ex[6]*inv, ex[7]*inv);
        int ci = 0; float best = d2[0];
        #pragma unroll
        for (int k = 1; k < KC; ++k) if (d2[k] < best) { best = d2[k]; ci = k; }
        cidx[s0 + t] = ci;
        #pragma unroll
        for (int k = 0; k < KC; ++k) {
            const u64 mk = __ballot(ci == k);
            if (t == 0 && mk) atomicAdd(&counts[k], (int)__popcll(mk));
        }
        kld[s0 + t] = 0.f;
    }

    // ================= decoder: d = relu(z Wd1 + bd1), col = ot =============
    {
        float w[16];
        #pragma unroll
        for (int k = 0; k < 16; ++k) w[k] = sm[XB + k*16 + ot];
        const float bb = bd1[ot];
        float dac[8];
        #pragma unroll
        for (int m = 0; m < 8; ++m) {
            const int r = st + 8*m;
            float s = bb;
            #pragma unroll
            for (int kc = 0; kc < 4; ++kc) {
                const float4 av = LD4(ZD + r*20 + kc*4);
                s = fmaf(av.x, w[kc*4+0], s); s = fmaf(av.y, w[kc*4+1], s);
                s = fmaf(av.z, w[kc*4+2], s); s = fmaf(av.w, w[kc*4+3], s);
            }
            dac[m] = fmaxf(s, 0.f);
        }
        __syncthreads();           // all z reads (d2 + decoder) done
        #pragma unroll
        for (int m = 0; m < 8; ++m) sm[ZD + (st + 8*m)*20 + ot] = dac[m];
        // d rows intra-wave -> xhat may read without barrier
    }

    // ================= xhat: K=16, halves from WA/WB_ (pre-staged) + rec ====
    float rp[8] = {0.f,0.f,0.f,0.f,0.f,0.f,0.f,0.f};
    #pragma unroll
    for (int h = 0; h < 2; ++h) {
        const int WH = h ? WB_ : WA;
        float accx[8][4];
        INIT84(accx, bd2, h*64 + job);
        #pragma unroll
        for (int kc = 0; kc < 4; ++kc) K4(accx, ZD, 20, kc, WH, 68, job, kc);
        #pragma unroll
        for (int m = 0; m < 8; ++m) {
            const int r = st + 8*m;
            const float4 xa = GL4(x[(size_t)(s0+r)*128 + h*64 + job]);
            float df;
            df=accx[m][0]-xa.x; rp[m]=fmaf(df,df,rp[m]);
            df=accx[m][1]-xa.y; rp[m]=fmaf(df,df,rp[m]);
            df=accx[m][2]-xa.z; rp[m]=fmaf(df,df,rp[m]);
            df=accx[m][3]-xa.w; rp[m]=fmaf(df,df,rp[m]);
            *reinterpret_cast<float4*>(&xhat[(size_t)(s0+r)*128 + h*64 + job]) =
                make_float4(accx[m][0],accx[m][1],accx[m][2],accx[m][3]);
        }
    }
    #pragma unroll
    for (int m = 0; m < 8; ++m) {
        float v = rp[m];
        v += __shfl_xor(v, 1); v += __shfl_xor(v, 2);
        v += __shfl_xor(v, 4); v += __shfl_xor(v, 8);
        if (ot == 0) rec[s0 + st + 8*m] = v * (1.f/128.f);
    }
}

// ---------------------------------------------------------------------------
__global__ void k_scan(const int* __restrict__ counts,
                       int* __restrict__ bases, int* __restrict__ cursors)
{
    if (threadIdx.x == 0) {
        int acc = 0;
        for (int k = 0; k < KC; ++k) { bases[k] = acc; cursors[k] = acc; acc += counts[k]; }
    }
}

__global__ __launch_bounds__(256) void k_scatter(
    const int* __restrict__ cidx, int* __restrict__ cursors, int* __restrict__ seg)
{
    const int s = blockIdx.x * 256 + threadIdx.x;
    const int lane = threadIdx.x & 63;
    const int ci = cidx[s];
    #pragma unroll
    for (int k = 0; k < KC; ++k) {
        const u64 mk = __ballot(ci == k);
        if (ci == k) {
            const int leader = __ffsll(mk) - 1;
            int base = 0;
            if (lane == leader) base = atomicAdd(&cursors[k], (int)__popcll(mk));
            base = __shfl(base, leader, 64);
            seg[base + (int)__popcll(mk & (((u64)1 << lane) - 1))] = s;
        }
    }
}

// ---------------------------------------------------------------------------
// k_heads: 64 gathered samples / 128 threads; cluster kk block-uniform.
// Same dbuf single-barrier staging for Wh1 (9 chunks) and Wh2 (4 chunks).
// ---------------------------------------------------------------------------
__global__ __launch_bounds__(128, 2) void k_heads(
    const float* __restrict__ x, const float* __restrict__ zread,
    const float* __restrict__ Wh1, const float* __restrict__ bh1,
    const float* __restrict__ Wh2, const float* __restrict__ bh2,
    const int* __restrict__ counts, const int* __restrict__ bases,
    const int* __restrict__ seg,
    float* __restrict__ surv)
{
    __shared__ float sm[SMW];
    __shared__ int idxs[64];
    const int t  = threadIdx.x;
    const int ot = t & 15, st = t >> 4;
    const int job = ot * 4;
    const int xr0 = t >> 1, xcc = (t & 1) * 8;
    const int wr  = t >> 3, wcc = (t & 7) * 8;

    int kk = -1, chunk = 0, pref = 0;
    #pragma unroll
    for (int q = 0; q < KC; ++q) {
        const int ck = (counts[q] + 63) >> 6;
        if (kk < 0) {
            if ((int)blockIdx.x < pref + ck) { kk = q; chunk = (int)blockIdx.x - pref; }
            pref += ck;
        }
    }
    if (kk < 0) return;                     // block-uniform, before any barrier
    kk    = __builtin_amdgcn_readfirstlane(kk);
    chunk = __builtin_amdgcn_readfirstlane(chunk);
    const int cnt  = __builtin_amdgcn_readfirstlane(counts[kk]);
    const int base = __builtin_amdgcn_readfirstlane(bases[kk]);

    if (t < 64) {
        const int i = chunk*64 + t;
        idxs[t] = seg[base + ((i < cnt) ? i : (cnt - 1))];
    }
    __syncthreads();
    const int irow = idxs[xr0];

    // ================= head L1: 9 chunks (z + 8 x), dbuf 1-barrier ==========
    {
        float acc1[8][4];
        INIT84(acc1, bh1, (size_t)kk*64 + job);
        // chunk0 (z) staged direct
        ST4(XA + xr0*20 + xcc)     = GL4(zread[(size_t)irow*16 + xcc]);
        ST4(XA + xr0*20 + xcc + 4) = GL4(zread[(size_t)irow*16 + xcc + 4]);
        ST4(WA + wr*68 + wcc)      = GL4(Wh1[((size_t)kk*144 + wr)*64 + wcc]);
        ST4(WA + wr*68 + wcc + 4)  = GL4(Wh1[((size_t)kk*144 + wr)*64 + wcc + 4]);
        // chunk1 regs (x cols 0..15, W rows 16..31)
        float4 rx0 = GL4(x[(size_t)irow*128 + xcc]);
        float4 rx1 = GL4(x[(size_t)irow*128 + xcc + 4]);
        float4 rw0 = GL4(Wh1[((size_t)kk*144 + 16 + wr)*64 + wcc]);
        float4 rw1 = GL4(Wh1[((size_t)kk*144 + 16 + wr)*64 + wcc + 4]);
        __syncthreads();
        #pragma unroll 1
        for (int c = 0; c < 9; ++c) {       // compute chunk c from buf[c&1]
            const int XC = (c & 1) ? XB : XA, WC = (c & 1) ? WB_ : WA;
            const int XN = (c & 1) ? XA : XB, WN = (c & 1) ? WA : WB_;
            if (c < 8) { STAGE_XB(XN); STAGE_WB(WN); }   // chunk c+1
            if (c < 7) {                                  // load chunk c+2
                rx0 = GL4(x[(size_t)irow*128 + (c+1)*16 + xcc]);
                rx1 = GL4(x[(size_t)irow*128 + (c+1)*16 + xcc + 4]);
                rw0 = GL4(Wh1[((size_t)kk*144 + 16 + (c+1)*16 + wr)*64 + wcc]);
                rw1 = GL4(Wh1[((size_t)kk*144 + 16 + (c+1)*16 + wr)*64 + wcc + 4]);
            }
            #pragma unroll
            for (int kc = 0; kc < 4; ++kc) K4(acc1, XC, 20, kc, WC, 68, job, kc);
            __syncthreads();
        }
        RELU84(acc1);
        WRITE_E(acc1);             // h1 -> EA (intra-wave rows)
    }

    // ================= head L2: 4 Wh2 chunks (padded), dbuf =================
    float acc2[8][4];
    {
        #pragma unroll
        for (int m = 0; m < 8; ++m) {
            acc2[m][0] = (job+0 < 50) ? bh2[(size_t)kk*50 + job+0] : 0.f;
            acc2[m][1] = (job+1 < 50) ? bh2[(size_t)kk*50 + job+1] : 0.f;
            acc2[m][2] = (job+2 < 50) ? bh2[(size_t)kk*50 + job+2] : 0.f;
            acc2[m][3] = (job+3 < 50) ? bh2[(size_t)kk*50 + job+3] : 0.f;
        }
    }
    #define LDWH2(RV0, RV1, CROW) do { \
        const size_t wrow_ = ((size_t)kk*64 + (CROW) + wr)*50; \
        RV0.x = (wcc+0 < 50) ? Wh2[wrow_ + wcc+0] : 0.f; \
        RV0.y = (wcc+1 < 50) ? Wh2[wrow_ + wcc+1] : 0.f; \
        RV0.z = (wcc+2 < 50) ? Wh2[wrow_ + wcc+2] : 0.f; \
        RV0.w = (wcc+3 < 50) ? Wh2[wrow_ + wcc+3] : 0.f; \
        RV1.x = (wcc+4 < 50) ? Wh2[wrow_ + wcc+4] : 0.f; \
        RV1.y = (wcc+5 < 50) ? Wh2[wrow_ + wcc+5] : 0.f; \
        RV1.z = (wcc+6 < 50) ? Wh2[wrow_ + wcc+6] : 0.f; \
        RV1.w = (wcc+7 < 50) ? Wh2[wrow_ + wcc+7] : 0.f; } while(0)
    {
        float4 rw0, rw1;
        LDWH2(rw0, rw1, 0);
        STAGE_WB(WA);                           // chunk0 (WA free: last Wh1
        LDWH2(rw0, rw1, 16);                    //  read barriered in loop)
        __syncthreads();
        #pragma unroll 1
        for (int c = 0; c < 4; ++c) {
            const int WC = (c & 1) ? WB_ : WA;
            const int WN = (c & 1) ? WA : WB_;
            if (c < 3) STAGE_WB(WN);
            if (c < 2) LDWH2(rw0, rw1, (c+2)*16);
            #pragma unroll
            for (int kc = 0; kc < 4; ++kc) K4(acc2, EA, 68, c*4 + kc, WC, 68, job, kc);
            __syncthreads();
        }
    }
    #undef LDWH2

    // ================= store surv (cols < 50, rows < cnt) ===================
    #pragma unroll
    for (int m = 0; m < 8; ++m) {
        const int r = st + 8*m;
        if (chunk*64 + r < cnt) {
            float* so = &surv[(size_t)idxs[r]*50 + job];   // 8B-aligned
            if (ot < 12) {
                *reinterpret_cast<float2*>(&so[0]) = make_float2(acc2[m][0], acc2[m][1]);
                *reinterpret_cast<float2*>(&so[2]) = make_float2(acc2[m][2], acc2[m][3]);
            } else if (ot == 12) {
                *reinterpret_cast<float2*>(&so[0]) = make_float2(acc2[m][0], acc2[m][1]);
            }
        }
    }
}

// ---------------------------------------------------------------------------
extern "C" void kernel_launch(void* const* d_in, const int* in_sizes, int n_in,
                              void* d_out, int out_size, void* d_ws, size_t ws_size,
                              hipStream_t stream)
{
    const float* x   = (const float*)d_in[0];
    const float* We1 = (const float*)d_in[1];
    const float* be1 = (const float*)d_in[2];
    const float* We2 = (const float*)d_in[3];
    const float* be2 = (const float*)d_in[4];
    const float* We3 = (const float*)d_in[5];
    const float* be3 = (const float*)d_in[6];
    const float* Wd1 = (const float*)d_in[7];
    const float* bd1 = (const float*)d_in[8];
    const float* Wd2 = (const float*)d_in[9];
    const float* bd2 = (const float*)d_in[10];
    const float* Wh1 = (const float*)d_in[11];
    const float* bh1 = (const float*)d_in[12];
    const float* Wh2 = (const float*)d_in[13];
    const float* bh2 = (const float*)d_in[14];
    const float* cen = (const float*)d_in[15];
    float* out = (float*)d_out;

    float* out_z  = out;
    float* out_q  = out + (size_t)NS * 16;
    float* out_sv = out + (size_t)NS * 24;
    float* out_xh = out + (size_t)NS * 74;
    float* out_rc = out + (size_t)NS * 202;
    float* out_kl = out + (size_t)NS * 203;

    int* cidx    = (int*)d_ws;       // [NS]
    int* counts  = cidx + NS;        // [8]
    int* bases   = counts + KC;      // [8]
    int* cursors = bases + KC;       // [8]
    int* seg     = cursors + KC;     // [NS]

    hipMemsetAsync(counts, 0, KC * sizeof(int), stream);

    k_enc<<<dim3(NS / 64), dim3(128), 0, stream>>>(
        x, We1, be1, We2, be2, We3, be3, Wd1, bd1, Wd2, bd2, cen,
        out_z, out_q, out_xh, out_rc, out_kl, cidx, counts);

    k_scan<<<dim3(1), dim3(64), 0, stream>>>(counts, bases, cursors);

    k_scatter<<<dim3(NS / 256), dim3(256), 0, stream>>>(cidx, cursors, seg);

    k_heads<<<dim3(NS / 64 + KC), dim3(128), 0, stream>>>(
        x, out_z, Wh1, bh1, Wh2, bh2, counts, bases, seg, out_sv);
}